// Round 7
// baseline (10618.492 us; speedup 1.0000x reference)
//
#include <hip/hip_runtime.h>

typedef __attribute__((ext_vector_type(8))) short s8v;   // 8 x bf16 (4 VGPRs)
typedef __attribute__((ext_vector_type(4))) float f4v;   // f32 MFMA accumulator
typedef __attribute__((ext_vector_type(4))) int   i4v;   // i8 MFMA operand/accumulator

#define BB 8
#define TT 500
#define UU 120
#define UP1 121
#define VV 128
#define HH 320
#define G4 1280

// ---------------- helpers ----------------
__device__ __forceinline__ unsigned short f2bf(float x) {
  unsigned u = __builtin_bit_cast(unsigned, x);
  unsigned r = (u + 0x7FFFu + ((u >> 16) & 1u)) >> 16;  // RNE
  return (unsigned short)r;
}
__device__ __forceinline__ float bf2f(unsigned hi16) {  // bf16 in high 16 bits
  return __builtin_bit_cast(float, hi16 & 0xFFFF0000u);
}
__device__ __forceinline__ float sigf(float x)   { return 1.f / (1.f + __expf(-x)); }
__device__ __forceinline__ float tanh_f(float x) { return 2.f / (1.f + __expf(-2.f * x)) - 1.f; }

// publish: agent-scope relaxed store (proven visible r3/r4/r6)
__device__ __forceinline__ void ast32(unsigned* p, unsigned v) {
  __hip_atomic_store(p, v, __ATOMIC_RELAXED, __HIP_MEMORY_SCOPE_AGENT);
}
// poll: SYSTEM-scope relaxed load — guaranteed L1+L2 bypass (sc0 sc1), reads
// the coherence point every time (defeats any cached-stale-line spin).
__device__ __forceinline__ unsigned aldsys(const unsigned* p) {
  return __hip_atomic_load((unsigned*)p, __ATOMIC_RELAXED, __HIP_MEMORY_SCOPE_SYSTEM);
}

// ---------------- prep: zero control words + out ----------------
__global__ void prep_zero(unsigned* ctl, float* out) {
  int i = blockIdx.x * blockDim.x + threadIdx.x;
  if (i < 256) ctl[i] = 0u;          // smax[0..3]
  if (i == 0) out[0] = 0.f;
}

// ---------------- abs-max per recurrent matrix (for i8 scales) ----------------
__global__ __launch_bounds__(256) void k_absmax(
    const float* __restrict__ w0, const float* __restrict__ w1,
    const float* __restrict__ w2, const float* __restrict__ w3,
    unsigned* __restrict__ smax)
{
  const int blk = blockIdx.x;                 // 1600 = 4 mats x 400
  const int s = blk / 400;
  const int off = (blk - s * 400) * 1024 + threadIdx.x * 4;
  const float* src = (s == 0) ? w0 : (s == 1) ? w1 : (s == 2) ? w2 : w3;
  float m = 0.f;
#pragma unroll
  for (int j = 0; j < 4; j++) m = fmaxf(m, fabsf(src[off + j]));
#pragma unroll
  for (int o = 32; o >= 1; o >>= 1) m = fmaxf(m, __shfl_xor(m, o));
  if ((threadIdx.x & 63) == 0) atomicMax(smax + s, __float_as_uint(m));
}

// ---------------- pack recurrent matrices into per-wave i8 MFMA fragment blobs ----------------
// blob[s][w][mt][kt][lane][16] i8 ; s: 0=Whh0 1=Whh1 2=Whhd 3=Wih1
// ALL use the unit-permuted A mapping (r5/r6-verified): A-row nn -> (unit nn>>2, gate nn&3).
// s=1 and s=3 share a COMMON scale (L1 fuses them into one K=640 accumulate).
__global__ __launch_bounds__(256) void k_pack(
    const float* __restrict__ w0, const float* __restrict__ w1,
    const float* __restrict__ w2, const float* __restrict__ w3,
    const unsigned* __restrict__ smax, char* __restrict__ wq)
{
  int gid = blockIdx.x * 256 + threadIdx.x;
  if (gid >= 1638400) return;
  int s = gid / 409600, r = gid - s * 409600;
  int j = r & 15, ln = (r >> 4) & 63, rem = r >> 10;
  int kt = rem % 5, mt = (rem / 5) % 10, w = rem / 50;
  int qq = ln >> 4, nn = ln & 15;
  int k = kt * 64 + qq * 16 + j;
  int unit = w * 40 + mt * 4 + (nn >> 2);
  int gr = (nn & 3) * HH + unit;
  const float* src = (s == 0) ? w0 : (s == 1) ? w1 : (s == 2) ? w2 : w3;
  float sm = __uint_as_float(smax[s]);
  if (s & 1) sm = fmaxf(__uint_as_float(smax[1]), __uint_as_float(smax[3]));
  float inv = 127.f / sm;
  wq[gid] = (char)__float2int_rn(src[gr * HH + k] * inv);
}

// ---------------- misc prep: bf16 staging + bias folds ----------------
__global__ void prep_w(
    const float* __restrict__ wih0, const float* __restrict__ xs,
    const float* __restrict__ ewo,  const float* __restrict__ dwo,
    const float* __restrict__ bih1, const float* __restrict__ bhh1,
    const float* __restrict__ bih0, const float* __restrict__ bhh0,
    ushort* __restrict__ wih0b, ushort* __restrict__ xsb,
    ushort* __restrict__ wob, ushort* __restrict__ dwob,
    float* __restrict__ b1p, float* __restrict__ b0s)
{
  int i = blockIdx.x * blockDim.x + threadIdx.x;
  if (i < 122880) {                        // Wih0 [1280][80] -> [1280][96] padded
    int row = i / 96, k = i - row * 96;
    wih0b[i] = (k < 80) ? f2bf(wih0[row * 80 + k]) : (ushort)0;
  } else if (i < 506880) {                 // xs [4000][80] -> [4000][96] padded
    int e = i - 122880;
    int row = e / 96, k = e - row * 96;
    xsb[e] = (k < 80) ? f2bf(xs[row * 80 + k]) : (ushort)0;
  } else if (i < 547840) {                 // enc_Wo [128][320]
    wob[i - 506880] = f2bf(ewo[i - 506880]);
  } else if (i < 588800) {                 // dec_Wo [128][320]
    dwob[i - 547840] = f2bf(dwo[i - 547840]);
  } else if (i < 590080) {                 // b1p [unit][gate] (r1-verified layout)
    int e = i - 588800;
    int uq = e >> 2, gq = e & 3;
    b1p[e] = bih1[gq * HH + uq] + bhh1[gq * HH + uq];
  } else if (i < 591360) {                 // b0s[gr] (gate-row order)
    int e = i - 590080;
    b0s[e] = bih0[e] + bhh0[e];
  }
}

// ---------------- xproj layer0 (bf16 MFMA, r1-verified), bf16 out ----------------
__global__ __launch_bounds__(256) void xproj0_mfma(
    const ushort* __restrict__ xsb, const ushort* __restrict__ wih0b,
    const float* __restrict__ b0s, ushort* __restrict__ xp0h)
{
  const int mt = blockIdx.x;                 // 250 tiles of 16 (b,t)-rows
  const int wave = threadIdx.x >> 6, lane = threadIdx.x & 63;
  const int q = lane >> 4, n16 = lane & 15;
  s8v a[3];
#pragma unroll
  for (int kt = 0; kt < 3; kt++)
    a[kt] = *(const s8v*)(xsb + (mt * 16 + n16) * 96 + kt * 32 + q * 8);
  for (int nt = wave; nt < 80; nt += 4) {
    s8v bf[3];
#pragma unroll
    for (int kt = 0; kt < 3; kt++)
      bf[kt] = *(const s8v*)(wih0b + (nt * 16 + n16) * 96 + kt * 32 + q * 8);
    f4v acc = {0.f, 0.f, 0.f, 0.f};
#pragma unroll
    for (int kt = 0; kt < 3; kt++)
      acc = __builtin_amdgcn_mfma_f32_16x16x32_bf16(a[kt], bf[kt], acc, 0, 0, 0);
    const int gr = nt * 16 + n16;            // D col = gate row
    const int gg = gr / HH;
    const int uu = gr - gg * HH;
    const float bias = b0s[gr];
#pragma unroll
    for (int r = 0; r < 4; r++) {
      int bt = mt * 16 + 4 * q + r;          // D row = (b,t) row
      xp0h[(size_t)bt * G4 + uu * 4 + gg] = f2bf(acc[r] + bias);
    }
  }
}

// ---------------- decoder input projection: one-hot gather, bf16 out ----------------
__global__ __launch_bounds__(256) void xprojd_g(
    const int* __restrict__ ys, const float* __restrict__ dWih,
    const float* __restrict__ dbih, const float* __restrict__ dbhh,
    ushort* __restrict__ xpdh)
{
  const int blk = blockIdx.x;                // 968 = 8 * 121
  const int b = blk / UP1, u = blk - b * UP1;
  int colv = -1;
  if (u > 0) colv = ys[b * UU + (u - 1)] - 1;
  for (int i = threadIdx.x; i < G4; i += 256) {
    int uu = i >> 2, gg = i & 3;
    int row = gg * HH + uu;
    float v = dbih[row] + dbhh[row];
    if (colv >= 0) v += dWih[row * 127 + colv];
    xpdh[((size_t)b * UP1 + u) * G4 + i] = f2bf(v);
  }
}

// ---------------- fused recurrences: 3 wgs, all recurrences INTRA-workgroup ----------------
// role 0: L0  h0[t+1] = cell(Whh0@h0[t] + xp0[t]); publishes h0 tagged u32 (write-once).
// role 1: L1  h1[t+1] = cell(Whh1@h1[t] + Wih1@h0[t+1] + b1) — fused K=640, common i8
//         scale; polls h0[t+1] wave-sliced with SYSTEM-scope loads; publishes h1 bf16.
// role 2: dec hd[t+1] = cell(Whhd@hd[t] + xpd[t]), 121 steps; publishes hd bf16.
// No ring, no throttle, single forward cross-WG edge (h0). One barrier per step.
__global__ __launch_bounds__(512)
__attribute__((amdgpu_waves_per_eu(1, 2)))
void lstm_fused(
    const char* __restrict__ wq, const unsigned* __restrict__ smaxp,
    const ushort* __restrict__ xp0h, const ushort* __restrict__ xpdh,
    const float* __restrict__ b1p,
    unsigned* __restrict__ h0u, ushort* __restrict__ h1h, ushort* __restrict__ hdh)
{
  const int role = blockIdx.x;
  const int tid = threadIdx.x;
  const int wave = tid >> 6, lane = tid & 63;
  const int q = lane >> 4, n16 = lane & 15;
  const int bcol = n16 & 7;
  const int ub = wave * 40;                  // this wave owns units [ub,ub+40)
  const bool two = (role == 1);

  __shared__ __align__(16) char wl[8][6][1024];   // 48 KB weight frag-groups (per-wave)
  __shared__ __align__(16) char hq[2][16][336];   // 10.5 KB dbuf own-h i8 (B operand)
  __shared__ __align__(16) char hqI[16][336];     // 5.25 KB h0 i8 (role 1 only)

  const char* blobS = wq + (role == 0 ? 0 : (role == 1 ? 409600 : 2 * 409600)) + wave * 51200;
  const char* blobI = wq + 3 * 409600 + wave * 51200;

  // ---- startup: weights into regs + LDS; zero hq/hqI ----
  i4v wregS[47], wregI[47];
  if (two) {
#pragma unroll
    for (int gi = 0; gi < 3; gi++) {
      *(i4v*)(&wl[wave][gi][lane * 16])     = *(const i4v*)(blobS + gi * 1024 + lane * 16);
      *(i4v*)(&wl[wave][3 + gi][lane * 16]) = *(const i4v*)(blobI + gi * 1024 + lane * 16);
    }
#pragma unroll
    for (int gi = 3; gi < 50; gi++) {
      wregS[gi - 3] = *(const i4v*)(blobS + gi * 1024 + lane * 16);
      wregI[gi - 3] = *(const i4v*)(blobI + gi * 1024 + lane * 16);
    }
  } else {
#pragma unroll
    for (int gi = 0; gi < 6; gi++)
      *(i4v*)(&wl[wave][gi][lane * 16]) = *(const i4v*)(blobS + gi * 1024 + lane * 16);
#pragma unroll
    for (int gi = 6; gi < 50; gi++)
      wregS[gi - 6] = *(const i4v*)(blobS + gi * 1024 + lane * 16);
  }
  for (int i = tid; i < 4032; i += 512) {
    if (i < 2688) ((unsigned*)hq)[i] = 0u;
    else ((unsigned*)hqI)[i - 2688] = 0u;
  }
  __syncthreads();

  float kf;
  if (role == 0)      kf = __uint_as_float(smaxp[0]) * (1.f / 16129.f);
  else if (role == 2) kf = __uint_as_float(smaxp[2]) * (1.f / 16129.f);
  else kf = fmaxf(__uint_as_float(smaxp[1]), __uint_as_float(smaxp[3])) * (1.f / 16129.f);

  const int steps = (role == 2) ? UP1 : TT;
  const ushort* xq = (role == 0) ? (xp0h + (size_t)bcol * TT * G4)
                                 : (xpdh + (size_t)bcol * UP1 * G4);
  float c[10];
#pragma unroll
  for (int m = 0; m < 10; m++) c[m] = 0.f;

  for (int t = 0; t < steps; t++) {
    const int pb = t & 1;

    if (two) {
      // ---- wave-sliced poll of h0[t+1] row `wave` (system-scope, L1-bypass) ----
      const unsigned* src = h0u + (size_t)(t + 1) * 2560 + wave * HH;
      unsigned v[5];
      int tries = 0;
      for (;;) {
#pragma unroll
        for (int j = 0; j < 5; j++) v[j] = aldsys(src + j * 64 + lane);
        unsigned a = v[0] & v[1] & v[2] & v[3] & v[4];
        if (__all((int)(a & 1u)) || ++tries > (1 << 17)) break;
        __builtin_amdgcn_s_sleep(2);
      }
#pragma unroll
      for (int j = 0; j < 5; j++)
        hqI[wave][j * 64 + lane] = (char)__float2int_rn(bf2f(v[j]) * 127.f);
    }
    // single per-step barrier (LDS only; covers hq/hqI write->read and
    // prev-step read -> this-step cell-write hazards)
    asm volatile("s_waitcnt lgkmcnt(0)\n\ts_barrier" ::: "memory");

#pragma unroll
    for (int P = 0; P < 2; P++) {
      // P=0: mts 5..9; P=1: mts 0..4 (low gi from LDS)
      uint2 xa[5]; f4v xf[5];
#pragma unroll
      for (int mi = 0; mi < 5; mi++) {
        const int m = P ? mi : 5 + mi;
        const int u = ub + m * 4 + q;
        if (two) xf[mi] = *(const f4v*)(b1p + u * 4);
        else     xa[mi] = *(const uint2*)(xq + (size_t)t * G4 + u * 4);
      }

      i4v acc[5];
#pragma unroll
      for (int mi = 0; mi < 5; mi++) { i4v z = {0, 0, 0, 0}; acc[mi] = z; }
#pragma unroll
      for (int kt = 0; kt < 5; kt++) {
        i4v bfS = *(const i4v*)(&hq[pb][n16][kt * 64 + q * 16]);
        i4v bfI;
        if (two) bfI = *(const i4v*)(&hqI[n16][kt * 64 + q * 16]);
#pragma unroll
        for (int mi = 0; mi < 5; mi++) {
          const int m = P ? mi : 5 + mi;
          const int gi = m * 5 + kt;
          if (two) {
            i4v wfS = (gi < 3) ? *(const i4v*)(&wl[wave][gi][lane * 16]) : wregS[gi - 3];
            acc[mi] = __builtin_amdgcn_mfma_i32_16x16x64_i8(wfS, bfS, acc[mi], 0, 0, 0);
            i4v wfI = (gi < 3) ? *(const i4v*)(&wl[wave][3 + gi][lane * 16]) : wregI[gi - 3];
            acc[mi] = __builtin_amdgcn_mfma_i32_16x16x64_i8(wfI, bfI, acc[mi], 0, 0, 0);
          } else {
            i4v wfS = (gi < 6) ? *(const i4v*)(&wl[wave][gi][lane * 16]) : wregS[gi - 6];
            acc[mi] = __builtin_amdgcn_mfma_i32_16x16x64_i8(wfS, bfS, acc[mi], 0, 0, 0);
          }
        }
      }

      // ---- cell: lane-local (unit = ub+m*4+q, batch n16) ----
#pragma unroll
      for (int mi = 0; mi < 5; mi++) {
        const int m = P ? mi : 5 + mi;
        float ad0, ad1, ad2, ad3;
        if (two) { ad0 = xf[mi][0]; ad1 = xf[mi][1]; ad2 = xf[mi][2]; ad3 = xf[mi][3]; }
        else {
          ad0 = bf2f(xa[mi].x << 16); ad1 = bf2f(xa[mi].x);
          ad2 = bf2f(xa[mi].y << 16); ad3 = bf2f(xa[mi].y);
        }
        float p0 = (float)acc[mi][0] * kf + ad0;
        float p1 = (float)acc[mi][1] * kf + ad1;
        float p2 = (float)acc[mi][2] * kf + ad2;
        float p3 = (float)acc[mi][3] * kf + ad3;
        float ig = sigf(p0), fg = sigf(p1), gv = tanh_f(p2), og = sigf(p3);
        c[m] = fg * c[m] + ig * gv;
        float hv = og * tanh_f(c[m]);
        const int u = ub + m * 4 + q;
        hq[pb ^ 1][n16][u] = (char)__float2int_rn(hv * 127.f);
        if (n16 < BB) {
          unsigned hb = (unsigned)f2bf(hv);
          if (role == 0)
            ast32(h0u + (size_t)(t + 1) * 2560 + n16 * HH + u, (hb << 16) | 1u);
          else if (role == 1)
            h1h[(size_t)(t + 1) * 5120 + n16 * HH + u] = (ushort)hb;
          else
            hdh[(size_t)(t + 1) * 5120 + n16 * HH + u] = (ushort)hb;
        }
      }
    }
  }
}

// ---------------- output projections: h bf16 [t][16][320] @ Wo^T -> out2[t][16][128] ----------------
__global__ __launch_bounds__(256) void proj_mfma(
    const ushort* __restrict__ hseq, const ushort* __restrict__ wo,
    const float* __restrict__ bo, float* __restrict__ out2)
{
  const int t = blockIdx.x;
  const int wave = threadIdx.x >> 6, lane = threadIdx.x & 63;
  const int q = lane >> 4, n16 = lane & 15;
  s8v a[10];
  const ushort* hp = hseq + (size_t)(t + 1) * 5120 + n16 * HH + q * 8;
#pragma unroll
  for (int kt = 0; kt < 10; kt++) a[kt] = *(const s8v*)(hp + kt * 32);
  for (int j = 0; j < 2; j++) {
    int nt = wave * 2 + j;
    s8v bf[10];
#pragma unroll
    for (int kt = 0; kt < 10; kt++)
      bf[kt] = *(const s8v*)(wo + (nt * 16 + n16) * HH + kt * 32 + q * 8);
    f4v acc = {0.f, 0.f, 0.f, 0.f};
#pragma unroll
    for (int kt = 0; kt < 10; kt++)
      acc = __builtin_amdgcn_mfma_f32_16x16x32_bf16(a[kt], bf[kt], acc, 0, 0, 0);
    int v = nt * 16 + n16;
    float bias = bo[v];
    if (q < 2) {
#pragma unroll
      for (int r = 0; r < 4; r++) {
        int b = 4 * q + r;                   // D row = batch
        out2[((size_t)t * 16 + b) * VV + v] = acc[r] + bias;
      }
    }
  }
}

// ---------------- per-cell logsumexp over V -> lb[b][t][u], ly[b][t][u] ----------------
__global__ __launch_bounds__(256) void lse_kernel(
    const float* __restrict__ enc2, const float* __restrict__ dec2,
    const int* __restrict__ ys, float* __restrict__ lb, float* __restrict__ ly)
{
  const int blk = blockIdx.x;                // 4000 = 8*500
  const int b = blk / TT, t = blk - b * TT;
  const int wave = threadIdx.x >> 6, lane = threadIdx.x & 63;
  const float* er = enc2 + ((size_t)t * 16 + b) * VV;
  const float e0 = er[lane], e1 = er[lane + 64];
  for (int u = wave; u < UP1; u += 4) {
    const float* dr = dec2 + ((size_t)u * 16 + b) * VV;
    float s0 = e0 + dr[lane], s1 = e1 + dr[lane + 64];
    float mx = fmaxf(s0, s1);
#pragma unroll
    for (int off = 32; off >= 1; off >>= 1) mx = fmaxf(mx, __shfl_xor(mx, off));
    float p = __expf(s0 - mx) + __expf(s1 - mx);
#pragma unroll
    for (int off = 32; off >= 1; off >>= 1) p += __shfl_xor(p, off);
    float lsev = mx + __logf(p);
    if (u < UU) {
      int y = ys[b * UU + u];                // in [1,127]
      float sy = (y < 64) ? __shfl(s0, y) : __shfl(s1, y - 64);
      if (lane == 0) ly[((size_t)b * TT + t) * UU + u] = sy - lsev;
    }
    if (lane == 0) lb[((size_t)b * TT + t) * UP1 + u] = s0 - lsev;
  }
}

// ---------------- forward DP: one wave per sample, barrier-free (shfl) ----------------
__global__ __launch_bounds__(64) void dp_kernel(
    const float* __restrict__ lb, const float* __restrict__ ly,
    const int* __restrict__ xlen, const int* __restrict__ ylen,
    float* __restrict__ out)
{
  const int b = blockIdx.x, l = threadIdx.x;
  const int tl = xlen[b], ul = ylen[b];
  const float NEG = -1e30f;
  const float* lbb = lb + (size_t)b * TT * UP1;
  const float* lyb = ly + (size_t)b * TT * UU;
  const int u1 = l, u2 = 64 + l;
  const bool has2 = (u2 <= UU);
  float a1 = (l == 0) ? 0.f : NEG, a2 = NEG;
  float nlb1 = 0.f, nly1 = 0.f, nlb2 = 0.f, nly2 = 0.f;
  { int tn = 1 - u1;
    if (tn >= 1 && tn < TT) nlb1 = lbb[(tn - 1) * UP1 + u1];
    if (u1 >= 1 && tn >= 0 && tn < TT) nly1 = lyb[tn * UU + (u1 - 1)]; }
  for (int d = 1; d <= TT - 1 + UU; d++) {
    float lb1 = nlb1, ly1 = nly1, lb2 = nlb2, ly2 = nly2;
    { int tn = d + 1 - u1;
      nlb1 = (tn >= 1 && tn < TT) ? lbb[(tn - 1) * UP1 + u1] : 0.f;
      nly1 = (u1 >= 1 && tn >= 0 && tn < TT) ? lyb[tn * UU + (u1 - 1)] : 0.f; }
    { int tn = d + 1 - u2;
      nlb2 = (has2 && tn >= 1 && tn < TT) ? lbb[(tn - 1) * UP1 + u2] : 0.f;
      nly2 = (has2 && tn >= 0 && tn < TT) ? lyb[tn * UU + (u2 - 1)] : 0.f; }
    float p1 = __shfl_up(a1, 1);
    float p2 = __shfl_up(a2, 1);
    float wz = __shfl(a1, 63);
    if (l == 0) p2 = wz;
    {
      const int t1 = d - u1;
      float v1 = NEG;
      if (t1 >= 0 && t1 < TT) {
        float x = (t1 >= 1) ? a1 + lb1 : NEG;
        float y = (u1 >= 1) ? p1 + ly1 : NEG;
        float m = fmaxf(x, y);
        v1 = (m <= -1e29f) ? NEG : m + __logf(1.f + __expf(-fabsf(x - y)));
        if (t1 == tl - 1 && u1 == ul) atomicAdd(out, -0.125f * (v1 + lbb[t1 * UP1 + u1]));
      }
      a1 = v1;
    }
    {
      const int t2 = d - u2;
      float v2 = NEG;
      if (has2 && t2 >= 0 && t2 < TT) {
        float x = (t2 >= 1) ? a2 + lb2 : NEG;
        float y = p2 + ly2;
        float m = fmaxf(x, y);
        v2 = (m <= -1e29f) ? NEG : m + __logf(1.f + __expf(-fabsf(x - y)));
        if (t2 == tl - 1 && u2 == ul) atomicAdd(out, -0.125f * (v2 + lbb[t2 * UP1 + u2]));
      }
      a2 = v2;
    }
  }
}

// ---------------- launch ----------------
extern "C" void kernel_launch(void* const* d_in, const int* in_sizes, int n_in,
                              void* d_out, int out_size, void* d_ws, size_t ws_size,
                              hipStream_t stream) {
  (void)in_sizes; (void)n_in; (void)out_size;
  const float* xs    = (const float*)d_in[0];
  const int*   ys    = (const int*)d_in[1];
  const int*   xlen  = (const int*)d_in[2];
  const int*   ylen  = (const int*)d_in[3];
  const float* eWih0 = (const float*)d_in[4];
  const float* eWhh0 = (const float*)d_in[5];
  const float* ebih0 = (const float*)d_in[6];
  const float* ebhh0 = (const float*)d_in[7];
  const float* eWih1 = (const float*)d_in[8];
  const float* eWhh1 = (const float*)d_in[9];
  const float* ebih1 = (const float*)d_in[10];
  const float* ebhh1 = (const float*)d_in[11];
  const float* eWo   = (const float*)d_in[12];
  const float* ebo   = (const float*)d_in[13];
  const float* dWih  = (const float*)d_in[15];
  const float* dWhh  = (const float*)d_in[16];
  const float* dbih  = (const float*)d_in[17];
  const float* dbhh  = (const float*)d_in[18];
  const float* dWo   = (const float*)d_in[19];
  const float* dbo   = (const float*)d_in[20];

  char* ws = (char*)d_ws;
  const size_t OFF_CTL   = 0;                     // smax[4]
  const size_t OFF_XP0H  = 1024;                  // [8][500][1280] bf16
  const size_t OFF_XPDH  = OFF_XP0H + 10240000;   // [8][121][1280] bf16
  const size_t OFF_H0    = OFF_XPDH + 2478080;    // [501][8][320] tagged u32
  const size_t OFF_H1    = OFF_H0   + 5130240;    // [501][16][320] bf16 (rows 0-7 used)
  const size_t OFF_HD    = OFF_H1   + 5130240;    // [122][16][320] bf16
  const size_t OFF_WQ    = OFF_HD   + 1249280;    // i8 blobs [4][409600]
  const size_t OFF_WIH0B = OFF_WQ   + 1638400;
  const size_t OFF_XSB   = OFF_WIH0B + 245760;
  const size_t OFF_WOB   = OFF_XSB  + 768000;
  const size_t OFF_DWOB  = OFF_WOB  + 81920;
  const size_t OFF_B1P   = OFF_DWOB + 81920;
  const size_t OFF_B0S   = OFF_B1P  + 5120;
  const size_t OFF_ENC2  = OFF_B0S  + 5120;       // 500*16*128 f32 = 4,096,000
  const size_t OFF_DEC2  = OFF_ENC2 + 4096000;    // 121*16*128 f32 =   991,232
  const size_t OFF_LB    = OFF_DEC2 + 991232;     // 8*500*121 f32  = 1,936,000
  const size_t OFF_LY    = OFF_LB   + 1936000;    // 8*500*120 f32  = 1,920,000
  const size_t TOTAL     = OFF_LY   + 1920000;    // ~36.9 MB
  if (ws_size < TOTAL) return;

  unsigned* ctl   = (unsigned*)(ws + OFF_CTL);
  unsigned* smax  = ctl;
  ushort*   xp0h  = (ushort*)(ws + OFF_XP0H);
  ushort*   xpdh  = (ushort*)(ws + OFF_XPDH);
  unsigned* h0    = (unsigned*)(ws + OFF_H0);
  ushort*   h1    = (ushort*)(ws + OFF_H1);
  ushort*   hd    = (ushort*)(ws + OFF_HD);
  char*     wq    = (char*)(ws + OFF_WQ);
  ushort*   wih0b = (ushort*)(ws + OFF_WIH0B);
  ushort*   xsb   = (ushort*)(ws + OFF_XSB);
  ushort*   wob   = (ushort*)(ws + OFF_WOB);
  ushort*   dwob  = (ushort*)(ws + OFF_DWOB);
  float*    b1p   = (float*)(ws + OFF_B1P);
  float*    b0s   = (float*)(ws + OFF_B0S);
  float*    enc2  = (float*)(ws + OFF_ENC2);
  float*    dec2  = (float*)(ws + OFF_DEC2);
  float*    lb    = (float*)(ws + OFF_LB);
  float*    ly    = (float*)(ws + OFF_LY);
  float*    out   = (float*)d_out;

  hipLaunchKernelGGL(prep_zero, dim3(1), dim3(256), 0, stream, ctl, out);
  hipLaunchKernelGGL(k_absmax, dim3(1600), dim3(256), 0, stream,
                     eWhh0, eWhh1, dWhh, eWih1, smax);
  hipLaunchKernelGGL(k_pack, dim3(6400), dim3(256), 0, stream,
                     eWhh0, eWhh1, dWhh, eWih1, smax, wq);
  hipLaunchKernelGGL(prep_w, dim3(2310), dim3(256), 0, stream,
                     eWih0, xs, eWo, dWo, ebih1, ebhh1, ebih0, ebhh0,
                     wih0b, xsb, wob, dwob, b1p, b0s);
  hipLaunchKernelGGL(xproj0_mfma, dim3(250), dim3(256), 0, stream, xsb, wih0b, b0s, xp0h);
  hipLaunchKernelGGL(xprojd_g, dim3(968), dim3(256), 0, stream, ys, dWih, dbih, dbhh, xpdh);
  hipLaunchKernelGGL(lstm_fused, dim3(3), dim3(512), 0, stream,
                     wq, smax, xp0h, xpdh, b1p, h0, h1, hd);
  hipLaunchKernelGGL(proj_mfma, dim3(500), dim3(256), 0, stream, h1, wob, ebo, enc2);
  hipLaunchKernelGGL(proj_mfma, dim3(121), dim3(256), 0, stream, hd, dwob, dbo, dec2);
  hipLaunchKernelGGL(lse_kernel, dim3(4000), dim3(256), 0, stream, enc2, dec2, ys, lb, ly);
  hipLaunchKernelGGL(dp_kernel, dim3(8), dim3(64), 0, stream, lb, ly, xlen, ylen, out);
}

// Round 8
// 3195.134 us; speedup vs baseline: 3.3233x; 3.3233x over previous
//
#include <hip/hip_runtime.h>

typedef __attribute__((ext_vector_type(8))) short s8v;   // 8 x bf16 (4 VGPRs)
typedef __attribute__((ext_vector_type(4))) float f4v;   // f32 MFMA accumulator
typedef __attribute__((ext_vector_type(4))) int   i4v;   // i8 MFMA operand/accumulator

#define BB 8
#define TT 500
#define UU 120
#define UP1 121
#define VV 128
#define HH 320
#define G4 1280

// ---------------- helpers ----------------
__device__ __forceinline__ unsigned short f2bf(float x) {
  unsigned u = __builtin_bit_cast(unsigned, x);
  unsigned r = (u + 0x7FFFu + ((u >> 16) & 1u)) >> 16;  // RNE
  return (unsigned short)r;
}
__device__ __forceinline__ float bf2f(unsigned hi16) {  // bf16 in high 16 bits
  return __builtin_bit_cast(float, hi16 & 0xFFFF0000u);
}
__device__ __forceinline__ float sigf(float x)   { return 1.f / (1.f + __expf(-x)); }
__device__ __forceinline__ float tanh_f(float x) { return 2.f / (1.f + __expf(-2.f * x)) - 1.f; }

// relaxed agent-scope atomics (sc1 path; proven transport r3/r4/r6)
__device__ __forceinline__ unsigned ald32(const unsigned* p) {
  return __hip_atomic_load((unsigned*)p, __ATOMIC_RELAXED, __HIP_MEMORY_SCOPE_AGENT);
}
__device__ __forceinline__ void ast32(unsigned* p, unsigned v) {
  __hip_atomic_store(p, v, __ATOMIC_RELAXED, __HIP_MEMORY_SCOPE_AGENT);
}

// ---------------- prep: tagged zeros for t=0 state + control ----------------
__global__ void prep_zero(unsigned* h0, unsigned* h1, unsigned* hd, unsigned* ctl, float* out) {
  int i = blockIdx.x * blockDim.x + threadIdx.x;
  if (i < 2560) { h0[i] = 1u; h1[i] = 1u; hd[i] = 1u; }   // t=0: 8x320 tagged zeros each
  if (i < 16 && blockIdx.x == 0) ctl[i] = 0u;             // smax[0..3]
  if (i == 0) out[0] = 0.f;
}

// ---------------- abs-max per recurrent matrix (for i8 scales) ----------------
__global__ __launch_bounds__(256) void k_absmax(
    const float* __restrict__ w0, const float* __restrict__ w1,
    const float* __restrict__ w2, const float* __restrict__ w3,
    unsigned* __restrict__ smax)
{
  const int blk = blockIdx.x;                 // 1600 = 4 mats x 400
  const int s = blk / 400;
  const int off = (blk - s * 400) * 1024 + threadIdx.x * 4;
  const float* src = (s == 0) ? w0 : (s == 1) ? w1 : (s == 2) ? w2 : w3;
  float m = 0.f;
#pragma unroll
  for (int j = 0; j < 4; j++) m = fmaxf(m, fabsf(src[off + j]));
#pragma unroll
  for (int o = 32; o >= 1; o >>= 1) m = fmaxf(m, __shfl_xor(m, o));
  if ((threadIdx.x & 63) == 0) atomicMax(smax + s, __float_as_uint(m));
}

// ---------------- pack recurrent mats into per-wave i8 frag blobs + misc prep ----------------
// blob[s][W][mt][kt][lane][16] i8; W in [0,20) owns units [W*16,W*16+16), mt in [0,4), kt in [0,5).
// A-row nn -> unit W*16+mt*4+(nn>>2), gate nn&3 (r5-r7 verified A mapping).
// s: 0=Whh0 1=Whh1 2=Whhd 3=Wih1; s=1,3 share a common scale (L1 K=640 fusion).
__global__ __launch_bounds__(256) void k_pack(
    const float* __restrict__ w0, const float* __restrict__ w1,
    const float* __restrict__ w2, const float* __restrict__ w3,
    const unsigned* __restrict__ smax, char* __restrict__ wq,
    const float* __restrict__ wih0, const float* __restrict__ xs,
    const float* __restrict__ ewo,  const float* __restrict__ dwo,
    const float* __restrict__ bih1, const float* __restrict__ bhh1,
    const float* __restrict__ bih0, const float* __restrict__ bhh0,
    ushort* __restrict__ wih0b, ushort* __restrict__ xsb,
    ushort* __restrict__ wob, ushort* __restrict__ dwob,
    float* __restrict__ b1p, float* __restrict__ b0s)
{
  int gid = blockIdx.x * 256 + threadIdx.x;
  if (gid < 1638400) {
    int s = gid / 409600, r = gid - s * 409600;
    int j = r & 15, ln = (r >> 4) & 63, rem = r >> 10;
    int kt = rem % 5, mt = (rem / 5) % 4, W = rem / 20;
    int qq = ln >> 4, nn = ln & 15;
    int k = kt * 64 + qq * 16 + j;
    int unit = W * 16 + mt * 4 + (nn >> 2);
    int gr = (nn & 3) * HH + unit;
    const float* src = (s == 0) ? w0 : (s == 1) ? w1 : (s == 2) ? w2 : w3;
    float sm = __uint_as_float(smax[s]);
    if (s & 1) sm = fmaxf(__uint_as_float(smax[1]), __uint_as_float(smax[3]));
    float inv = 127.f / sm;
    wq[gid] = (char)__float2int_rn(src[gr * HH + k] * inv);
    return;
  }
  int i = gid - 1638400;
  if (i < 122880) {                        // Wih0 [1280][80] -> [1280][96] padded
    int row = i / 96, k = i - row * 96;
    wih0b[i] = (k < 80) ? f2bf(wih0[row * 80 + k]) : (ushort)0;
  } else if (i < 506880) {                 // xs [4000][80] -> [4000][96] padded
    int e = i - 122880;
    int row = e / 96, k = e - row * 96;
    xsb[e] = (k < 80) ? f2bf(xs[row * 80 + k]) : (ushort)0;
  } else if (i < 547840) {                 // enc_Wo [128][320]
    wob[i - 506880] = f2bf(ewo[i - 506880]);
  } else if (i < 588800) {                 // dec_Wo [128][320]
    dwob[i - 547840] = f2bf(dwo[i - 547840]);
  } else if (i < 590080) {                 // b1p [unit][gate]
    int e = i - 588800;
    int uq = e >> 2, gq = e & 3;
    b1p[e] = bih1[gq * HH + uq] + bhh1[gq * HH + uq];
  } else if (i < 591360) {                 // b0s[gr] gate-row order
    int e = i - 590080;
    b0s[e] = bih0[e] + bhh0[e];
  }
}

// ---------------- xproj layer0 (bf16 MFMA, r1-verified), bf16 out ----------------
__global__ __launch_bounds__(256) void xproj0_mfma(
    const ushort* __restrict__ xsb, const ushort* __restrict__ wih0b,
    const float* __restrict__ b0s, ushort* __restrict__ xp0h)
{
  const int mt = blockIdx.x;                 // 250 tiles of 16 (b,t)-rows
  const int wave = threadIdx.x >> 6, lane = threadIdx.x & 63;
  const int q = lane >> 4, n16 = lane & 15;
  s8v a[3];
#pragma unroll
  for (int kt = 0; kt < 3; kt++)
    a[kt] = *(const s8v*)(xsb + (mt * 16 + n16) * 96 + kt * 32 + q * 8);
  for (int nt = wave; nt < 80; nt += 4) {
    s8v bf[3];
#pragma unroll
    for (int kt = 0; kt < 3; kt++)
      bf[kt] = *(const s8v*)(wih0b + (nt * 16 + n16) * 96 + kt * 32 + q * 8);
    f4v acc = {0.f, 0.f, 0.f, 0.f};
#pragma unroll
    for (int kt = 0; kt < 3; kt++)
      acc = __builtin_amdgcn_mfma_f32_16x16x32_bf16(a[kt], bf[kt], acc, 0, 0, 0);
    const int gr = nt * 16 + n16;            // D col = gate row
    const int gg = gr / HH;
    const int uu = gr - gg * HH;
    const float bias = b0s[gr];
#pragma unroll
    for (int r = 0; r < 4; r++) {
      int bt = mt * 16 + 4 * q + r;          // D row = (b,t) row
      xp0h[(size_t)bt * G4 + uu * 4 + gg] = f2bf(acc[r] + bias);
    }
  }
}

// ---------------- decoder input projection: one-hot gather, bf16 out ----------------
__global__ __launch_bounds__(256) void xprojd_g(
    const int* __restrict__ ys, const float* __restrict__ dWih,
    const float* __restrict__ dbih, const float* __restrict__ dbhh,
    ushort* __restrict__ xpdh)
{
  const int blk = blockIdx.x;                // 968 = 8 * 121
  const int b = blk / UP1, u = blk - b * UP1;
  int colv = -1;
  if (u > 0) colv = ys[b * UU + (u - 1)] - 1;
  for (int i = threadIdx.x; i < G4; i += 256) {
    int uu = i >> 2, gg = i & 3;
    int row = gg * HH + uu;
    float v = dbih[row] + dbhh[row];
    if (colv >= 0) v += dWih[row * 127 + colv];
    xpdh[((size_t)b * UP1 + u) * G4 + i] = f2bf(v);
  }
}

// ---------------- fused recurrences: 3 stages x 5 wgs x 256 thr ----------------
// stage 0: L0  h0[t+1]=cell(Whh0@h0[t]+xp0[t]);  stage 1: L1 (fused K=640, +h0[t+1]);
// stage 2: dec (121 steps). ALL h transport = tagged write-once u32 via L3 (proven).
// 256-thr WGs -> >=208 VGPR budget (r3-measured): weights mts1-3 in regs, mt0 in LDS.
// One lgkm-only barrier/step; wave-sliced polls (2 batch rows/wave).
__global__ __launch_bounds__(256, 1) void lstm_fused(
    const char* __restrict__ wq, const unsigned* __restrict__ smaxp,
    const ushort* __restrict__ xp0h, const ushort* __restrict__ xpdh,
    const float* __restrict__ b1p,
    unsigned* __restrict__ h0u, unsigned* __restrict__ h1u, unsigned* __restrict__ hdu)
{
  const int role = blockIdx.x / 5;
  const int gw = blockIdx.x - role * 5;
  const int tid = threadIdx.x;
  const int wave = tid >> 6, lane = tid & 63;
  const int q = lane >> 4, n16 = lane & 15;
  const int bcol = n16 & 7;
  const int W = gw * 4 + wave;               // layer-wave [0,20)
  const int ub = W * 16;                     // owns units [ub, ub+16)
  const bool two = (role == 1);

  __shared__ __align__(16) char wl[4][10][1024];   // 40 KB (L0/dec use slots 0-4)
  __shared__ __align__(16) char hq[2][16][336];    // 10.5 KB dbuf own-h i8
  __shared__ __align__(16) char hqI[2][16][336];   // 10.5 KB dbuf h0 i8 (L1 only)

  const char* blobS = wq + (role == 0 ? 0 : (role == 1 ? 409600 : 819200)) + W * 20480;
  const char* blobI = wq + 1228800 + W * 20480;    // Wih1

  // ---- startup: mt0 -> LDS, mts1-3 -> regs; zero hq rows 8-15 ----
  i4v wregS[15], wregI[15];
#pragma unroll
  for (int kt = 0; kt < 5; kt++) {
    *(i4v*)(&wl[wave][kt][lane * 16]) = *(const i4v*)(blobS + kt * 1024 + lane * 16);
    if (two)
      *(i4v*)(&wl[wave][5 + kt][lane * 16]) = *(const i4v*)(blobI + kt * 1024 + lane * 16);
  }
#pragma unroll
  for (int mt = 1; mt < 4; mt++)
#pragma unroll
    for (int kt = 0; kt < 5; kt++) {
      wregS[(mt - 1) * 5 + kt] = *(const i4v*)(blobS + (mt * 5 + kt) * 1024 + lane * 16);
      if (two)
        wregI[(mt - 1) * 5 + kt] = *(const i4v*)(blobI + (mt * 5 + kt) * 1024 + lane * 16);
    }
  for (int i = tid; i < 672; i += 256) {
    ((unsigned*)&hq[0][8][0])[i] = 0u;  ((unsigned*)&hq[1][8][0])[i] = 0u;
    ((unsigned*)&hqI[0][8][0])[i] = 0u; ((unsigned*)&hqI[1][8][0])[i] = 0u;
  }
  __syncthreads();

  float kf;
  if (role == 0)      kf = __uint_as_float(smaxp[0]) * (1.f / 16129.f);
  else if (role == 2) kf = __uint_as_float(smaxp[2]) * (1.f / 16129.f);
  else kf = fmaxf(__uint_as_float(smaxp[1]), __uint_as_float(smaxp[3])) * (1.f / 16129.f);

  const int steps = (role == 2) ? UP1 : TT;
  unsigned* hbuf = (role == 0) ? h0u : ((role == 1) ? h1u : hdu);

  f4v xf[4];                                 // L1: constant bias addend, preloaded
  if (two) {
#pragma unroll
    for (int mt = 0; mt < 4; mt++) xf[mt] = *(const f4v*)(b1p + (ub + mt * 4 + q) * 4);
  }
  float c0 = 0.f, c1 = 0.f, c2 = 0.f, c3 = 0.f;

  for (int t = 0; t < steps; t++) {
    const int pb = t & 1;

    // ---- poll own h[t] rows {wave, wave+4} (+ h0[t+1] for L1), relay -> LDS i8 ----
    {
      const unsigned* s0 = hbuf + (size_t)t * 2560 + wave * HH;
      const unsigned* s1 = hbuf + (size_t)t * 2560 + (wave + 4) * HH;
      const unsigned* i0 = h0u + (size_t)(t + 1) * 2560 + wave * HH;
      const unsigned* i1 = h0u + (size_t)(t + 1) * 2560 + (wave + 4) * HH;
      unsigned pa[10], pi[10];
      int tries = 0;
      for (;;) {
#pragma unroll
        for (int j = 0; j < 5; j++) {
          pa[j]     = ald32(s0 + j * 64 + lane);
          pa[5 + j] = ald32(s1 + j * 64 + lane);
        }
        unsigned m = pa[0];
#pragma unroll
        for (int j = 1; j < 10; j++) m &= pa[j];
        if (two) {
#pragma unroll
          for (int j = 0; j < 5; j++) {
            pi[j]     = ald32(i0 + j * 64 + lane);
            pi[5 + j] = ald32(i1 + j * 64 + lane);
          }
#pragma unroll
          for (int j = 0; j < 10; j++) m &= pi[j];
        }
        if (__all((int)(m & 1u)) || ++tries > (1 << 17)) break;
        if (tries > 32) __builtin_amdgcn_s_sleep(2);
      }
#pragma unroll
      for (int j = 0; j < 5; j++) {
        hq[pb][wave][j * 64 + lane]     = (char)__float2int_rn(bf2f(pa[j]) * 127.f);
        hq[pb][wave + 4][j * 64 + lane] = (char)__float2int_rn(bf2f(pa[5 + j]) * 127.f);
      }
      if (two) {
#pragma unroll
        for (int j = 0; j < 5; j++) {
          hqI[pb][wave][j * 64 + lane]     = (char)__float2int_rn(bf2f(pi[j]) * 127.f);
          hqI[pb][wave + 4][j * 64 + lane] = (char)__float2int_rn(bf2f(pi[5 + j]) * 127.f);
        }
      }
    }
    // single per-step barrier, LDS-only (publishes stay fire-and-forget)
    asm volatile("s_waitcnt lgkmcnt(0)\n\ts_barrier" ::: "memory");

    // ---- x addends (L0/dec: per-step bf16x4) ----
    uint2 xa[4];
    if (!two) {
      const ushort* xq = (role == 0) ? (xp0h + ((size_t)bcol * TT + t) * G4)
                                     : (xpdh + ((size_t)bcol * UP1 + t) * G4);
#pragma unroll
      for (int mt = 0; mt < 4; mt++) xa[mt] = *(const uint2*)(xq + (ub + mt * 4 + q) * 4);
    }

    // ---- MFMAs: 4 mts x 5 kts (L1: x2 matrices) ----
    i4v acc[4];
#pragma unroll
    for (int mt = 0; mt < 4; mt++) { i4v z = {0, 0, 0, 0}; acc[mt] = z; }
#pragma unroll
    for (int kt = 0; kt < 5; kt++) {
      i4v bS = *(const i4v*)(&hq[pb][n16][kt * 64 + q * 16]);
      i4v bI;
      if (two) bI = *(const i4v*)(&hqI[pb][n16][kt * 64 + q * 16]);
#pragma unroll
      for (int mt = 0; mt < 4; mt++) {
        i4v wS = (mt == 0) ? *(const i4v*)(&wl[wave][kt][lane * 16]) : wregS[(mt - 1) * 5 + kt];
        acc[mt] = __builtin_amdgcn_mfma_i32_16x16x64_i8(wS, bS, acc[mt], 0, 0, 0);
        if (two) {
          i4v wI = (mt == 0) ? *(const i4v*)(&wl[wave][5 + kt][lane * 16]) : wregI[(mt - 1) * 5 + kt];
          acc[mt] = __builtin_amdgcn_mfma_i32_16x16x64_i8(wI, bI, acc[mt], 0, 0, 0);
        }
      }
    }

    // ---- cell (lane-local: unit ub+mt*4+q, batch n16) + tagged publish ----
#pragma unroll
    for (int mt = 0; mt < 4; mt++) {
      float ad0, ad1, ad2, ad3;
      if (two) { ad0 = xf[mt][0]; ad1 = xf[mt][1]; ad2 = xf[mt][2]; ad3 = xf[mt][3]; }
      else {
        ad0 = bf2f(xa[mt].x << 16); ad1 = bf2f(xa[mt].x);
        ad2 = bf2f(xa[mt].y << 16); ad3 = bf2f(xa[mt].y);
      }
      float p0 = (float)acc[mt][0] * kf + ad0;
      float p1 = (float)acc[mt][1] * kf + ad1;
      float p2 = (float)acc[mt][2] * kf + ad2;
      float p3 = (float)acc[mt][3] * kf + ad3;
      float ig = sigf(p0), fg = sigf(p1), gv = tanh_f(p2), og = sigf(p3);
      float cc = (mt == 0) ? c0 : (mt == 1) ? c1 : (mt == 2) ? c2 : c3;
      cc = fg * cc + ig * gv;
      if (mt == 0) c0 = cc; else if (mt == 1) c1 = cc; else if (mt == 2) c2 = cc; else c3 = cc;
      float hv = og * tanh_f(cc);
      if (n16 < BB)
        ast32(hbuf + (size_t)(t + 1) * 2560 + n16 * HH + (ub + mt * 4 + q),
              (((unsigned)f2bf(hv)) << 16) | 1u);
    }
  }
}

// ---------------- output projections: tagged h [t][8][320]u32 @ Wo^T -> out2[t][16][128] ----------------
__global__ __launch_bounds__(256) void proj_mfma(
    const unsigned* __restrict__ hseq, const ushort* __restrict__ wo,
    const float* __restrict__ bo, float* __restrict__ out2)
{
  const int t = blockIdx.x;
  const int wave = threadIdx.x >> 6, lane = threadIdx.x & 63;
  const int q = lane >> 4, n16 = lane & 15;
  union F { unsigned u[4]; s8v v; };
  F a[10];
  const unsigned long long* hp =
      (const unsigned long long*)hseq + (size_t)(t + 1) * 1280 + n16 * 160 + q * 4;
#pragma unroll
  for (int kt = 0; kt < 10; kt++)
#pragma unroll
    for (int j = 0; j < 4; j++) {
      unsigned long long r = (n16 < BB) ? hp[kt * 16 + j] : 0ull;
      unsigned lo = (unsigned)r, hi = (unsigned)(r >> 32);
      a[kt].u[j] = (lo >> 16) | (hi & 0xFFFF0000u);
    }
  for (int j = 0; j < 2; j++) {
    int nt = wave * 2 + j;
    s8v bf[10];
#pragma unroll
    for (int kt = 0; kt < 10; kt++)
      bf[kt] = *(const s8v*)(wo + (nt * 16 + n16) * HH + kt * 32 + q * 8);
    f4v acc = {0.f, 0.f, 0.f, 0.f};
#pragma unroll
    for (int kt = 0; kt < 10; kt++)
      acc = __builtin_amdgcn_mfma_f32_16x16x32_bf16(a[kt].v, bf[kt], acc, 0, 0, 0);
    int v = nt * 16 + n16;
    float bias = bo[v];
    if (q < 2) {
#pragma unroll
      for (int r = 0; r < 4; r++) {
        int b = 4 * q + r;                   // D row = batch
        out2[((size_t)t * 16 + b) * VV + v] = acc[r] + bias;
      }
    }
  }
}

// ---------------- per-cell logsumexp over V -> lb[b][t][u], ly[b][t][u] ----------------
__global__ __launch_bounds__(256) void lse_kernel(
    const float* __restrict__ enc2, const float* __restrict__ dec2,
    const int* __restrict__ ys, float* __restrict__ lb, float* __restrict__ ly)
{
  const int blk = blockIdx.x;                // 4000 = 8*500
  const int b = blk / TT, t = blk - b * TT;
  const int wave = threadIdx.x >> 6, lane = threadIdx.x & 63;
  const float* er = enc2 + ((size_t)t * 16 + b) * VV;
  const float e0 = er[lane], e1 = er[lane + 64];
  for (int u = wave; u < UP1; u += 4) {
    const float* dr = dec2 + ((size_t)u * 16 + b) * VV;
    float s0 = e0 + dr[lane], s1 = e1 + dr[lane + 64];
    float mx = fmaxf(s0, s1);
#pragma unroll
    for (int off = 32; off >= 1; off >>= 1) mx = fmaxf(mx, __shfl_xor(mx, off));
    float p = __expf(s0 - mx) + __expf(s1 - mx);
#pragma unroll
    for (int off = 32; off >= 1; off >>= 1) p += __shfl_xor(p, off);
    float lsev = mx + __logf(p);
    if (u < UU) {
      int y = ys[b * UU + u];                // in [1,127]
      float sy = (y < 64) ? __shfl(s0, y) : __shfl(s1, y - 64);
      if (lane == 0) ly[((size_t)b * TT + t) * UU + u] = sy - lsev;
    }
    if (lane == 0) lb[((size_t)b * TT + t) * UP1 + u] = s0 - lsev;
  }
}

// ---------------- forward DP: one wave per sample, barrier-free (shfl) ----------------
__global__ __launch_bounds__(64) void dp_kernel(
    const float* __restrict__ lb, const float* __restrict__ ly,
    const int* __restrict__ xlen, const int* __restrict__ ylen,
    float* __restrict__ out)
{
  const int b = blockIdx.x, l = threadIdx.x;
  const int tl = xlen[b], ul = ylen[b];
  const float NEG = -1e30f;
  const float* lbb = lb + (size_t)b * TT * UP1;
  const float* lyb = ly + (size_t)b * TT * UU;
  const int u1 = l, u2 = 64 + l;
  const bool has2 = (u2 <= UU);
  float a1 = (l == 0) ? 0.f : NEG, a2 = NEG;
  float nlb1 = 0.f, nly1 = 0.f, nlb2 = 0.f, nly2 = 0.f;
  { int tn = 1 - u1;
    if (tn >= 1 && tn < TT) nlb1 = lbb[(tn - 1) * UP1 + u1];
    if (u1 >= 1 && tn >= 0 && tn < TT) nly1 = lyb[tn * UU + (u1 - 1)]; }
  for (int d = 1; d <= TT - 1 + UU; d++) {
    float lb1 = nlb1, ly1 = nly1, lb2 = nlb2, ly2 = nly2;
    { int tn = d + 1 - u1;
      nlb1 = (tn >= 1 && tn < TT) ? lbb[(tn - 1) * UP1 + u1] : 0.f;
      nly1 = (u1 >= 1 && tn >= 0 && tn < TT) ? lyb[tn * UU + (u1 - 1)] : 0.f; }
    { int tn = d + 1 - u2;
      nlb2 = (has2 && tn >= 1 && tn < TT) ? lbb[(tn - 1) * UP1 + u2] : 0.f;
      nly2 = (has2 && tn >= 0 && tn < TT) ? lyb[tn * UU + (u2 - 1)] : 0.f; }
    float p1 = __shfl_up(a1, 1);
    float p2 = __shfl_up(a2, 1);
    float wz = __shfl(a1, 63);
    if (l == 0) p2 = wz;
    {
      const int t1 = d - u1;
      float v1 = NEG;
      if (t1 >= 0 && t1 < TT) {
        float x = (t1 >= 1) ? a1 + lb1 : NEG;
        float y = (u1 >= 1) ? p1 + ly1 : NEG;
        float m = fmaxf(x, y);
        v1 = (m <= -1e29f) ? NEG : m + __logf(1.f + __expf(-fabsf(x - y)));
        if (t1 == tl - 1 && u1 == ul) atomicAdd(out, -0.125f * (v1 + lbb[t1 * UP1 + u1]));
      }
      a1 = v1;
    }
    {
      const int t2 = d - u2;
      float v2 = NEG;
      if (has2 && t2 >= 0 && t2 < TT) {
        float x = (t2 >= 1) ? a2 + lb2 : NEG;
        float y = p2 + ly2;
        float m = fmaxf(x, y);
        v2 = (m <= -1e29f) ? NEG : m + __logf(1.f + __expf(-fabsf(x - y)));
        if (t2 == tl - 1 && u2 == ul) atomicAdd(out, -0.125f * (v2 + lbb[t2 * UP1 + u2]));
      }
      a2 = v2;
    }
  }
}

// ---------------- launch ----------------
extern "C" void kernel_launch(void* const* d_in, const int* in_sizes, int n_in,
                              void* d_out, int out_size, void* d_ws, size_t ws_size,
                              hipStream_t stream) {
  (void)in_sizes; (void)n_in; (void)out_size;
  const float* xs    = (const float*)d_in[0];
  const int*   ys    = (const int*)d_in[1];
  const int*   xlen  = (const int*)d_in[2];
  const int*   ylen  = (const int*)d_in[3];
  const float* eWih0 = (const float*)d_in[4];
  const float* eWhh0 = (const float*)d_in[5];
  const float* ebih0 = (const float*)d_in[6];
  const float* ebhh0 = (const float*)d_in[7];
  const float* eWih1 = (const float*)d_in[8];
  const float* eWhh1 = (const float*)d_in[9];
  const float* ebih1 = (const float*)d_in[10];
  const float* ebhh1 = (const float*)d_in[11];
  const float* eWo   = (const float*)d_in[12];
  const float* ebo   = (const float*)d_in[13];
  const float* dWih  = (const float*)d_in[15];
  const float* dWhh  = (const float*)d_in[16];
  const float* dbih  = (const float*)d_in[17];
  const float* dbhh  = (const float*)d_in[18];
  const float* dWo   = (const float*)d_in[19];
  const float* dbo   = (const float*)d_in[20];

  char* ws = (char*)d_ws;
  const size_t OFF_CTL   = 0;                     // smax[4]
  const size_t OFF_XP0H  = 1024;                  // [8][500][1280] bf16
  const size_t OFF_XPDH  = OFF_XP0H + 10240000;   // [8][121][1280] bf16
  const size_t OFF_H0    = OFF_XPDH + 2478080;    // [501][8][320] tagged u32
  const size_t OFF_H1    = OFF_H0   + 5130240;    // [501][8][320] tagged u32
  const size_t OFF_HD    = OFF_H1   + 5130240;    // [122][8][320] tagged u32
  const size_t OFF_WQ    = OFF_HD   + 1249280;    // i8 blobs [4][409600]
  const size_t OFF_WIH0B = OFF_WQ   + 1638400;
  const size_t OFF_XSB   = OFF_WIH0B + 245760;
  const size_t OFF_WOB   = OFF_XSB  + 768000;
  const size_t OFF_DWOB  = OFF_WOB  + 81920;
  const size_t OFF_B1P   = OFF_DWOB + 81920;
  const size_t OFF_B0S   = OFF_B1P  + 5120;
  const size_t OFF_ENC2  = OFF_B0S  + 5120;       // 500*16*128 f32
  const size_t OFF_DEC2  = OFF_ENC2 + 4096000;    // 121*16*128 f32
  const size_t OFF_LB    = OFF_DEC2 + 991232;     // 8*500*121 f32
  const size_t OFF_LY    = OFF_LB   + 1936000;    // 8*500*120 f32
  const size_t TOTAL     = OFF_LY   + 1920000;    // ~36.9 MB
  if (ws_size < TOTAL) return;

  unsigned* ctl   = (unsigned*)(ws + OFF_CTL);
  unsigned* smax  = ctl;
  ushort*   xp0h  = (ushort*)(ws + OFF_XP0H);
  ushort*   xpdh  = (ushort*)(ws + OFF_XPDH);
  unsigned* h0    = (unsigned*)(ws + OFF_H0);
  unsigned* h1    = (unsigned*)(ws + OFF_H1);
  unsigned* hd    = (unsigned*)(ws + OFF_HD);
  char*     wq    = (char*)(ws + OFF_WQ);
  ushort*   wih0b = (ushort*)(ws + OFF_WIH0B);
  ushort*   xsb   = (ushort*)(ws + OFF_XSB);
  ushort*   wob   = (ushort*)(ws + OFF_WOB);
  ushort*   dwob  = (ushort*)(ws + OFF_DWOB);
  float*    b1p   = (float*)(ws + OFF_B1P);
  float*    b0s   = (float*)(ws + OFF_B0S);
  float*    enc2  = (float*)(ws + OFF_ENC2);
  float*    dec2  = (float*)(ws + OFF_DEC2);
  float*    lb    = (float*)(ws + OFF_LB);
  float*    ly    = (float*)(ws + OFF_LY);
  float*    out   = (float*)d_out;

  hipLaunchKernelGGL(prep_zero, dim3(10), dim3(256), 0, stream, h0, h1, hd, ctl, out);
  hipLaunchKernelGGL(k_absmax, dim3(1600), dim3(256), 0, stream,
                     eWhh0, eWhh1, dWhh, eWih1, smax);
  hipLaunchKernelGGL(k_pack, dim3(8710), dim3(256), 0, stream,
                     eWhh0, eWhh1, dWhh, eWih1, smax, wq,
                     eWih0, xs, eWo, dWo, ebih1, ebhh1, ebih0, ebhh0,
                     wih0b, xsb, wob, dwob, b1p, b0s);
  hipLaunchKernelGGL(xproj0_mfma, dim3(250), dim3(256), 0, stream, xsb, wih0b, b0s, xp0h);
  hipLaunchKernelGGL(xprojd_g, dim3(968), dim3(256), 0, stream, ys, dWih, dbih, dbhh, xpdh);
  hipLaunchKernelGGL(lstm_fused, dim3(15), dim3(256), 0, stream,
                     wq, smax, xp0h, xpdh, b1p, h0, h1, hd);
  hipLaunchKernelGGL(proj_mfma, dim3(500), dim3(256), 0, stream, h1, wob, ebo, enc2);
  hipLaunchKernelGGL(proj_mfma, dim3(121), dim3(256), 0, stream, hd, dwob, dbo, dec2);
  hipLaunchKernelGGL(lse_kernel, dim3(4000), dim3(256), 0, stream, enc2, dec2, ys, lb, ly);
  hipLaunchKernelGGL(dp_kernel, dim3(8), dim3(64), 0, stream, lb, ly, xlen, ylen, out);
}